// Round 3
// baseline (223.157 us; speedup 1.0000x reference)
//
#include <hip/hip_runtime.h>
#include <cstdint>
#include <cstddef>

// ---------------------------------------------------------------------------
// GCN 2-layer + 2 heads. N=100000 (<2^17), E=1.6M.
//   CSR:    slack-capacity segmented buckets (pass1/pass2), line-padded gcur
//   pass2:  + fused cast xh = bf16(dinv ⊙ x)  (R2: kills k_cast launch)
//   pull1:  aggh = bf16(dinv ⊙ (Â-gather))   16-lane-per-node, bcast col,
//           R2: 1-deep software pipeline (next col batch in regs, issued
//           before current gathers -> col latency fully hidden)
//   gemm12: g2h = bf16(dinv ⊙ relu(aggh@W1+b1)@W2)  -- fused bf16 MFMA,
//           h1 lives only in LDS, XOR-swizzled tiles, 80KB -> 2 blocks/CU
//   pull2:  same pipelined gather + relu + both heads fused
// ---------------------------------------------------------------------------

#define MAXC 512   // max coarse buckets (N <= 131072)
#define CAP  6144  // slots per bucket; mean 4093, sigma 64 -> no overflow
#define SEG  3456  // max edges per pass1 block (LDS-staged)
#define GPAD 16    // gcur stride in ints (one counter per 64B line)

typedef __attribute__((ext_vector_type(8))) short bf16x8;
typedef __attribute__((ext_vector_type(4))) float f32x4;

__device__ __forceinline__ float blo(unsigned int u) {
  return __uint_as_float(u << 16);
}
__device__ __forceinline__ float bhi(unsigned int u) {
  return __uint_as_float(u & 0xffff0000u);
}
__device__ __forceinline__ unsigned short f2b(float f) {  // RNE pack
  unsigned int u = __float_as_uint(f);
  unsigned int r = u + 0x7fffu + ((u >> 16) & 1u);
  return (unsigned short)(r >> 16);
}

// --- pipelined 16-lane-group gather-accumulate over one node's edge list ---
// cols for batch t+8 are issued BEFORE batch t's gathers, hiding col latency
// under gather latency. All loads in-bounds by construction.
__device__ __forceinline__ void gacc(const uint2* __restrict__ tab,
                                     const int* __restrict__ cp,
                                     int m, int q, float4& acc) {
  int nfull = m & ~7;
  int t = 0;
  if (nfull) {
    int cb[8];
#pragma unroll
    for (int i = 0; i < 8; ++i) cb[i] = cp[i];
    for (t = 0; t < nfull; t += 8) {
      int ca[8];
#pragma unroll
      for (int i = 0; i < 8; ++i) ca[i] = cb[i];
      int tn = t + 8;
      if (tn < nfull) {
#pragma unroll
        for (int i = 0; i < 8; ++i) cb[i] = cp[tn + i];
      }
      uint2 v[8];
#pragma unroll
      for (int i = 0; i < 8; ++i) v[i] = tab[(size_t)ca[i] * 16 + q];
      acc.x += ((blo(v[0].x) + blo(v[1].x)) + (blo(v[2].x) + blo(v[3].x)))
             + ((blo(v[4].x) + blo(v[5].x)) + (blo(v[6].x) + blo(v[7].x)));
      acc.y += ((bhi(v[0].x) + bhi(v[1].x)) + (bhi(v[2].x) + bhi(v[3].x)))
             + ((bhi(v[4].x) + bhi(v[5].x)) + (bhi(v[6].x) + bhi(v[7].x)));
      acc.z += ((blo(v[0].y) + blo(v[1].y)) + (blo(v[2].y) + blo(v[3].y)))
             + ((blo(v[4].y) + blo(v[5].y)) + (blo(v[6].y) + blo(v[7].y)));
      acc.w += ((bhi(v[0].y) + bhi(v[1].y)) + (bhi(v[2].y) + bhi(v[3].y)))
             + ((bhi(v[4].y) + bhi(v[5].y)) + (bhi(v[6].y) + bhi(v[7].y)));
    }
  }
  if (t + 4 <= m) {
    int i0 = cp[t], i1 = cp[t + 1], i2 = cp[t + 2], i3 = cp[t + 3];
    uint2 v0 = tab[(size_t)i0 * 16 + q], v1 = tab[(size_t)i1 * 16 + q];
    uint2 v2 = tab[(size_t)i2 * 16 + q], v3 = tab[(size_t)i3 * 16 + q];
    acc.x += (blo(v0.x) + blo(v1.x)) + (blo(v2.x) + blo(v3.x));
    acc.y += (bhi(v0.x) + bhi(v1.x)) + (bhi(v2.x) + bhi(v3.x));
    acc.z += (blo(v0.y) + blo(v1.y)) + (blo(v2.y) + blo(v3.y));
    acc.w += (bhi(v0.y) + bhi(v1.y)) + (bhi(v2.y) + bhi(v3.y));
    t += 4;
  }
  for (; t < m; ++t) {
    int i0 = cp[t];
    uint2 v0 = tab[(size_t)i0 * 16 + q];
    acc.x += blo(v0.x); acc.y += bhi(v0.x);
    acc.z += blo(v0.y); acc.w += bhi(v0.y);
  }
}

// --- bucket cursors: segmented regions of CAP slots, line-padded ---
__global__ void k_binit(int* __restrict__ gcur, int nc) {
  int b = blockIdx.x * 256 + threadIdx.x;
  if (b < nc) gcur[b * GPAD] = b * CAP;
}

// --- pass1: block-local counting sort by bucket, coalesced write-out ---
__global__ __launch_bounds__(256) void k_pass1(const int* __restrict__ src,
                                               const int* __restrict__ dst,
                                               int* __restrict__ gcur,
                                               int* __restrict__ P,
                                               int E, int nc, int seg) {
  __shared__ int hist[MAXC];
  __shared__ int lofs[MAXC];
  __shared__ int base[MAXC];
  __shared__ int sbuf[SEG];
  __shared__ unsigned short dbuf[SEG];
  __shared__ int ssc[256];
  int tid = threadIdx.x;
  int start = blockIdx.x * seg;
  int end = min(E, start + seg);
  int cnt = end - start;
  if (cnt <= 0) return;
  for (int i = tid; i < MAXC; i += 256) hist[i] = 0;
  __syncthreads();
  for (int i = start + tid; i < end; i += 256)
    atomicAdd(&hist[dst[i] >> 8], 1);
  __syncthreads();
  int p0 = hist[2 * tid], p1 = hist[2 * tid + 1];
  int ps = p0 + p1;
  ssc[tid] = ps;
  __syncthreads();
  for (int off = 1; off < 256; off <<= 1) {
    int t = (tid >= off) ? ssc[tid - off] : 0;
    __syncthreads();
    ssc[tid] += t;
    __syncthreads();
  }
  int pe = ssc[tid] - ps;
  lofs[2 * tid] = pe;
  lofs[2 * tid + 1] = pe + p0;
  __syncthreads();
  for (int b = tid; b < nc; b += 256) {
    int h = hist[b];
    base[b] = (h ? atomicAdd(&gcur[b * GPAD], h) : 0) - lofs[b];
  }
  __syncthreads();
  for (int i = tid; i < MAXC; i += 256) hist[i] = lofs[i];
  __syncthreads();
  for (int i = start + tid; i < end; i += 256) {
    int d = dst[i];
    int b = d >> 8;
    int r = atomicAdd(&hist[b], 1);
    sbuf[r] = src[i] | ((d & 255) << 17);
    dbuf[r] = (unsigned short)b;
  }
  __syncthreads();
  for (int j = tid; j < cnt; j += 256) {
    P[base[dbuf[j]] + j] = sbuf[j];
  }
}

// --- per-bucket: LDS count+scan -> rs/c/dinv, place col, then cast xh ---
__global__ __launch_bounds__(256) void k_pass2(const int* __restrict__ P,
                                               const int* __restrict__ gcur,
                                               int* __restrict__ rs,
                                               int* __restrict__ c,
                                               float* __restrict__ dinv,
                                               int* __restrict__ col,
                                               const float* __restrict__ x,
                                               unsigned int* __restrict__ xh,
                                               int N) {
  __shared__ int sh[256];
  __shared__ int lcur[256];
  __shared__ float sdi[256];
  int tid = threadIdx.x;
  int node0 = blockIdx.x << 8;
  int begin = blockIdx.x * CAP;
  int end = gcur[blockIdx.x * GPAD];
  sh[tid] = 0;
  __syncthreads();
  for (int i = begin + tid; i < end; i += 256)
    atomicAdd(&sh[P[i] >> 17], 1);
  __syncthreads();
  int s = sh[tid];
  for (int off = 1; off < 256; off <<= 1) {
    int t = (tid >= off) ? sh[tid - off] : 0;
    __syncthreads();
    sh[tid] += t;
    __syncthreads();
  }
  int excl = sh[tid] - s;
  int node = node0 + tid;
  float di = rsqrtf((float)(s + 1));
  sdi[tid] = di;
  if (node < N) {
    rs[node] = begin + excl;
    c[node] = s;
    dinv[node] = di;
  }
  lcur[tid] = begin + excl;
  __syncthreads();
  for (int i = begin + tid; i < end; i += 256) {
    int p = P[i];
    int pos = atomicAdd(&lcur[p >> 17], 1);
    col[pos] = p & 0x1FFFF;
  }
  // fused cast: xh[node] = bf16(dinv[node] * x[node]) for this block's nodes
  int nrem = min(256, N - node0);
  if (nrem <= 0) return;
  for (int i = tid; i < nrem * 16; i += 256) {
    int r = i >> 4, qq = i & 15;
    float d2 = sdi[r];
    float4 v = reinterpret_cast<const float4*>(x)[(size_t)(node0 + r) * 16 + qq];
    uint2 o;
    o.x = (unsigned int)f2b(v.x * d2) | ((unsigned int)f2b(v.y * d2) << 16);
    o.y = (unsigned int)f2b(v.z * d2) | ((unsigned int)f2b(v.w * d2) << 16);
    reinterpret_cast<uint2*>(xh)[(size_t)(node0 + r) * 16 + qq] = o;
  }
}

// --- pull1: 16-lane group per node, pipelined gather ---
__global__ __launch_bounds__(256) void k_pull1(const unsigned int* __restrict__ xh,
                                               const int* __restrict__ rs,
                                               const int* __restrict__ cnt,
                                               const int* __restrict__ col,
                                               const float* __restrict__ dinv,
                                               unsigned int* __restrict__ aggh,
                                               int n) {
  int tid = threadIdx.x;
  int q = tid & 15;
  int node = (blockIdx.x * 256 + tid) >> 4;  // 16 nodes per block
  bool valid = node < n;
  int nidx = valid ? node : 0;
  int start = rs[nidx];
  int m = valid ? cnt[nidx] : 0;
  const uint2* xr = reinterpret_cast<const uint2*>(xh);
  float4 acc = {0.f, 0.f, 0.f, 0.f};
  gacc(xr, col + start, m, q, acc);
  if (valid) {
    uint2 sv = xr[(size_t)node * 16 + q];  // self term: xh = bf16(di*x)
    acc.x += blo(sv.x); acc.y += bhi(sv.x);
    acc.z += blo(sv.y); acc.w += bhi(sv.y);
    float di = dinv[node];
    uint2 o;
    o.x = (unsigned int)f2b(acc.x * di) | ((unsigned int)f2b(acc.y * di) << 16);
    o.y = (unsigned int)f2b(acc.z * di) | ((unsigned int)f2b(acc.w * di) << 16);
    reinterpret_cast<uint2*>(aggh)[(size_t)node * 16 + q] = o;
  }
}

// --- fused gemm12: g2h = bf16(dinv ⊙ relu(aggh@W1+b1)@W2), bf16 MFMA ---
// LDS (80KB, 2 blocks/CU): aggh[128][64]bf16 @0, W1t[128][64]bf16 @16K,
// W2t[64][128]bf16 @32K, h1[128][128]bf16 / C2[128][64]f32 (reused) @48K.
// All tiles XOR-swizzled (T2).
#define OFF_W1T 16384
#define OFF_W2T 32768
#define OFF_H1  49152
__global__ __launch_bounds__(256) void k_gemm12(
    const unsigned int* __restrict__ aggh,
    const float* __restrict__ W1, const float* __restrict__ b1,
    const float* __restrict__ W2, const float* __restrict__ dinv,
    unsigned int* __restrict__ g2h, int n) {
  __shared__ __align__(16) char smem[81920];
  int tid = threadIdx.x;
  int lane = tid & 63;
  int wid = tid >> 6;
  int lr = lane & 15, lg = lane >> 4;
  int wr = wid >> 1, wc = wid & 1;
  // stage W1t bf16 [ncol=128][k=64]
  {
    int nrow = tid >> 1, h = tid & 1;
    unsigned int pk[16];
#pragma unroll
    for (int q = 0; q < 16; ++q) {
      unsigned short a = f2b(W1[(size_t)(h * 32 + 2 * q) * 128 + nrow]);
      unsigned short bq = f2b(W1[(size_t)(h * 32 + 2 * q + 1) * 128 + nrow]);
      pk[q] = (unsigned int)a | ((unsigned int)bq << 16);
    }
#pragma unroll
    for (int cc = 0; cc < 4; ++cc) {
      uint4 v = make_uint4(pk[cc * 4], pk[cc * 4 + 1], pk[cc * 4 + 2], pk[cc * 4 + 3]);
      int byte = nrow * 128 + ((h * 64 + cc * 16) ^ ((nrow & 7) << 4));
      *reinterpret_cast<uint4*>(smem + OFF_W1T + byte) = v;
    }
  }
  // stage W2t bf16 [ncol=64][k=128]
  {
    int nrow = tid >> 2, qt = tid & 3;
    unsigned int pk[16];
#pragma unroll
    for (int q = 0; q < 16; ++q) {
      unsigned short a = f2b(W2[(size_t)(qt * 32 + 2 * q) * 64 + nrow]);
      unsigned short bq = f2b(W2[(size_t)(qt * 32 + 2 * q + 1) * 64 + nrow]);
      pk[q] = (unsigned int)a | ((unsigned int)bq << 16);
    }
#pragma unroll
    for (int cc = 0; cc < 4; ++cc) {
      uint4 v = make_uint4(pk[cc * 4], pk[cc * 4 + 1], pk[cc * 4 + 2], pk[cc * 4 + 3]);
      int byte = nrow * 256 + ((qt * 64 + cc * 16) ^ ((nrow & 7) << 4));
      *reinterpret_cast<uint4*>(smem + OFF_W2T + byte) = v;
    }
  }
  float bias[4];
#pragma unroll
  for (int ni = 0; ni < 4; ++ni) bias[ni] = b1[wc * 64 + ni * 16 + lr];

  int ntiles = (n + 127) >> 7;
  for (int tile = blockIdx.x; tile < ntiles; tile += gridDim.x) {
    int row0 = tile << 7;
    __syncthreads();
#pragma unroll
    for (int j = 0; j < 4; ++j) {
      int idx = tid + 256 * j;
      int r = idx >> 3, u = idx & 7;
      uint4 v = make_uint4(0u, 0u, 0u, 0u);
      int row = row0 + r;
      if (row < n) v = reinterpret_cast<const uint4*>(aggh)[(size_t)row * 8 + u];
      int byte = r * 128 + ((u * 16) ^ ((r & 7) << 4));
      *reinterpret_cast<uint4*>(smem + byte) = v;
    }
    __syncthreads();
    f32x4 acc1[4][4];
#pragma unroll
    for (int mi = 0; mi < 4; ++mi)
#pragma unroll
      for (int ni = 0; ni < 4; ++ni) {
        f32x4 z = {0.f, 0.f, 0.f, 0.f};
        acc1[mi][ni] = z;
      }
#pragma unroll
    for (int kk = 0; kk < 2; ++kk) {
      int kb = kk * 64 + lg * 16;
      bf16x8 af[4], bfq[4];
#pragma unroll
      for (int mi = 0; mi < 4; ++mi) {
        int r = wr * 64 + mi * 16 + lr;
        af[mi] = *reinterpret_cast<const bf16x8*>(smem + r * 128 + (kb ^ ((r & 7) << 4)));
      }
#pragma unroll
      for (int ni = 0; ni < 4; ++ni) {
        int nr = wc * 64 + ni * 16 + lr;
        bfq[ni] = *reinterpret_cast<const bf16x8*>(smem + OFF_W1T + nr * 128 + (kb ^ ((nr & 7) << 4)));
      }
#pragma unroll
      for (int mi = 0; mi < 4; ++mi)
#pragma unroll
        for (int ni = 0; ni < 4; ++ni)
          acc1[mi][ni] = __builtin_amdgcn_mfma_f32_16x16x32_bf16(
              af[mi], bfq[ni], acc1[mi][ni], 0, 0, 0);
    }
#pragma unroll
    for (int mi = 0; mi < 4; ++mi) {
      int m0 = wr * 64 + mi * 16 + lg * 4;
#pragma unroll
      for (int ni = 0; ni < 4; ++ni) {
        int kcol = wc * 64 + ni * 16 + lr;
#pragma unroll
        for (int rj = 0; rj < 4; ++rj) {
          float v = fmaxf(acc1[mi][ni][rj] + bias[ni], 0.f);
          int mm = m0 + rj;
          int byte = mm * 256 + ((kcol * 2) ^ ((mm & 15) << 4));
          *reinterpret_cast<unsigned short*>(smem + OFF_H1 + byte) = f2b(v);
        }
      }
    }
    __syncthreads();
    f32x4 acc2[4][2];
#pragma unroll
    for (int mi = 0; mi < 4; ++mi)
#pragma unroll
      for (int ni = 0; ni < 2; ++ni) {
        f32x4 z = {0.f, 0.f, 0.f, 0.f};
        acc2[mi][ni] = z;
      }
#pragma unroll
    for (int kk = 0; kk < 4; ++kk) {
      int kb = kk * 64 + lg * 16;
      bf16x8 af[4], bfq[2];
#pragma unroll
      for (int mi = 0; mi < 4; ++mi) {
        int m = wr * 64 + mi * 16 + lr;
        af[mi] = *reinterpret_cast<const bf16x8*>(smem + OFF_H1 + m * 256 + (kb ^ ((m & 15) << 4)));
      }
#pragma unroll
      for (int ni = 0; ni < 2; ++ni) {
        int nr = wc * 32 + ni * 16 + lr;
        bfq[ni] = *reinterpret_cast<const bf16x8*>(smem + OFF_W2T + nr * 256 + (kb ^ ((nr & 7) << 4)));
      }
#pragma unroll
      for (int mi = 0; mi < 4; ++mi)
#pragma unroll
        for (int ni = 0; ni < 2; ++ni)
          acc2[mi][ni] = __builtin_amdgcn_mfma_f32_16x16x32_bf16(
              af[mi], bfq[ni], acc2[mi][ni], 0, 0, 0);
    }
    __syncthreads();
#pragma unroll
    for (int mi = 0; mi < 4; ++mi) {
      int m0 = wr * 64 + mi * 16 + lg * 4;
#pragma unroll
      for (int ni = 0; ni < 2; ++ni) {
        int nn = wc * 32 + ni * 16 + lr;
#pragma unroll
        for (int rj = 0; rj < 4; ++rj) {
          int mm = m0 + rj;
          int byte = mm * 256 + ((nn * 4) ^ ((mm & 15) << 4));
          *reinterpret_cast<float*>(smem + OFF_H1 + byte) = acc2[mi][ni][rj];
        }
      }
    }
    __syncthreads();
#pragma unroll
    for (int j = 0; j < 8; ++j) {
      int idx = tid + 256 * j;
      int r = idx >> 4, c4 = idx & 15;
      int row = row0 + r;
      if (row < n) {
        float4 v = *reinterpret_cast<const float4*>(
            smem + OFF_H1 + r * 256 + ((c4 * 16) ^ ((r & 15) << 4)));
        float di = dinv[row];
        uint2 o;
        o.x = (unsigned int)f2b(v.x * di) | ((unsigned int)f2b(v.y * di) << 16);
        o.y = (unsigned int)f2b(v.z * di) | ((unsigned int)f2b(v.w * di) << 16);
        reinterpret_cast<uint2*>(g2h)[(size_t)row * 16 + c4] = o;
      }
    }
  }
}

// --- pull2: 16-lane group per node, pipelined gather, relu + both heads ---
__global__ __launch_bounds__(256) void k_pull2(const unsigned int* __restrict__ g2h,
                                               const int* __restrict__ rs,
                                               const int* __restrict__ cnt,
                                               const int* __restrict__ col,
                                               const float* __restrict__ dinv,
                                               const float* __restrict__ b,
                                               const float* __restrict__ Wd,
                                               const float* __restrict__ Wp,
                                               const float* __restrict__ bd,
                                               const float* __restrict__ bp,
                                               float* __restrict__ out, int n) {
  int tid = threadIdx.x;
  int q = tid & 15;
  int node = (blockIdx.x * 256 + tid) >> 4;
  bool valid = node < n;
  int nidx = valid ? node : 0;
  int start = rs[nidx];
  int m = valid ? cnt[nidx] : 0;
  const uint2* gr = reinterpret_cast<const uint2*>(g2h);
  float4 acc = {0.f, 0.f, 0.f, 0.f};
  gacc(gr, col + start, m, q, acc);
  {
    uint2 sv = gr[(size_t)nidx * 16 + q];  // self term
    acc.x += blo(sv.x); acc.y += bhi(sv.x);
    acc.z += blo(sv.y); acc.w += bhi(sv.y);
  }
  float di = dinv[nidx];
  float4 b4 = *reinterpret_cast<const float4*>(b + q * 4);
  float4 wd4 = *reinterpret_cast<const float4*>(Wd + q * 4);
  float4 wp4 = *reinterpret_cast<const float4*>(Wp + q * 4);
  float vx = fmaxf(fmaf(acc.x, di, b4.x), 0.f);
  float vy = fmaxf(fmaf(acc.y, di, b4.y), 0.f);
  float vz = fmaxf(fmaf(acc.z, di, b4.z), 0.f);
  float vw = fmaxf(fmaf(acc.w, di, b4.w), 0.f);
  float dsum = vx * wd4.x + vy * wd4.y + vz * wd4.z + vw * wd4.w;
  float psum = vx * wp4.x + vy * wp4.y + vz * wp4.z + vw * wp4.w;
#pragma unroll
  for (int off = 1; off < 16; off <<= 1) {
    dsum += __shfl_xor(dsum, off);
    psum += __shfl_xor(psum, off);
  }
  if (valid && q == 0) {
    out[node] = dsum + bd[0];
    out[n + node] = psum + bp[0];
  }
}

extern "C" void kernel_launch(void* const* d_in, const int* in_sizes, int n_in,
                              void* d_out, int out_size, void* d_ws, size_t ws_size,
                              hipStream_t stream) {
  const float* x  = (const float*)d_in[0];
  const int*   ei = (const int*)d_in[1];
  const float* W1 = (const float*)d_in[2];
  const float* b1 = (const float*)d_in[3];
  const float* W2 = (const float*)d_in[4];
  const float* b2 = (const float*)d_in[5];
  const float* Wd = (const float*)d_in[6];
  const float* bd = (const float*)d_in[7];
  const float* Wp = (const float*)d_in[8];
  const float* bp = (const float*)d_in[9];
  float* out = (float*)d_out;

  const int N = in_sizes[0] / 64;
  const int E = in_sizes[1] / 2;
  const int* src = ei;
  const int* dst = ei + E;
  const int nc = (N + 255) >> 8;

  char* ws = (char*)d_ws;
  size_t off = 0;
  auto alloc = [&](size_t bytes) -> void* {
    size_t a = (off + 255) & ~(size_t)255;
    off = a + bytes;
    return (void*)(ws + a);
  };

  int*   gcur = (int*)alloc((size_t)MAXC * GPAD * 4);
  int*   rs   = (int*)alloc((size_t)N * 4);
  int*   c    = (int*)alloc((size_t)N * 4);
  float* dinv = (float*)alloc((size_t)N * 4);
  int*   P    = (int*)alloc((size_t)nc * CAP * 4);
  int*   col  = (int*)alloc((size_t)nc * CAP * 4);
  unsigned int* xh   = (unsigned int*)alloc((size_t)N * 64 * 2);
  unsigned int* aggh = (unsigned int*)alloc((size_t)N * 64 * 2);
  unsigned int* g2h  = (unsigned int*)alloc((size_t)N * 64 * 2);
  (void)ws_size; (void)n_in; (void)out_size;

  k_binit<<<(nc + 255) / 256, 256, 0, stream>>>(gcur, nc);

  int nb1 = 512;
  int seg = (E + nb1 - 1) / nb1;
  while (seg > SEG) { nb1 *= 2; seg = (E + nb1 - 1) / nb1; }
  k_pass1<<<nb1, 256, 0, stream>>>(src, dst, gcur, P, E, nc, seg);
  k_pass2<<<nc, 256, 0, stream>>>(P, gcur, rs, c, dinv, col, x, xh, N);

  k_pull1<<<(N + 15) / 16, 256, 0, stream>>>(xh, rs, c, col, dinv, aggh, N);
  k_gemm12<<<512, 256, 0, stream>>>(aggh, W1, b1, W2, dinv, g2h, N);
  k_pull2<<<(N + 15) / 16, 256, 0, stream>>>(g2h, rs, c, col, dinv, b2, Wd, Wp, bd, bp, out, N);
}

// Round 4
// 220.305 us; speedup vs baseline: 1.0129x; 1.0129x over previous
//
#include <hip/hip_runtime.h>
#include <cstdint>
#include <cstddef>

// ---------------------------------------------------------------------------
// GCN 2-layer + 2 heads. N=100000 (<2^17), E=1.6M.
//   CSR:    slack-capacity segmented buckets (pass1/pass2), line-padded gcur
//           R3: relative cursors (gcur memset 0, +b*CAP at use) -> no k_binit;
//           wave-shuffle scans (1 barrier vs 16)
//   pass2:  + fused cast xh = bf16(dinv ⊙ x)
//   pulls:  R3: 8-lane group per node, uint4 (16B/lane) gathers -> each vmem
//           instr moves 8 edges (2x instr efficiency vs R2), head reduce 3 steps
//   gemm12: g2h = bf16(dinv ⊙ relu(aggh@W1+b1)@W2)  fused bf16 MFMA,
//           h1 LDS-only, XOR-swizzled tiles, 80KB -> 2 blocks/CU
// ---------------------------------------------------------------------------

#define MAXC 512   // max coarse buckets (N <= 131072)
#define CAP  6144  // slots per bucket; mean 4093, sigma 64 -> no overflow
#define SEG  3456  // max edges per pass1 block (LDS-staged)
#define GPAD 16    // gcur stride in ints (one counter per 64B line)

typedef __attribute__((ext_vector_type(8))) short bf16x8;
typedef __attribute__((ext_vector_type(4))) float f32x4;

__device__ __forceinline__ float blo(unsigned int u) {
  return __uint_as_float(u << 16);
}
__device__ __forceinline__ float bhi(unsigned int u) {
  return __uint_as_float(u & 0xffff0000u);
}
__device__ __forceinline__ unsigned short f2b(float f) {  // RNE pack
  unsigned int u = __float_as_uint(f);
  unsigned int r = u + 0x7fffu + ((u >> 16) & 1u);
  return (unsigned short)(r >> 16);
}

// --- 8-lane-group gather-accumulate: lane owns 8 features (uint4/row) ---
__device__ __forceinline__ void gacc8(const uint4* __restrict__ tab,
                                      const int* __restrict__ cp,
                                      int m, int q8, float a[8]) {
  int t = 0;
  for (; t + 8 <= m; t += 8) {
    int c0 = cp[t],     c1 = cp[t + 1], c2 = cp[t + 2], c3 = cp[t + 3];
    int c4 = cp[t + 4], c5 = cp[t + 5], c6 = cp[t + 6], c7 = cp[t + 7];
    uint4 v0 = tab[(size_t)c0 * 8 + q8], v1 = tab[(size_t)c1 * 8 + q8];
    uint4 v2 = tab[(size_t)c2 * 8 + q8], v3 = tab[(size_t)c3 * 8 + q8];
    uint4 v4 = tab[(size_t)c4 * 8 + q8], v5 = tab[(size_t)c5 * 8 + q8];
    uint4 v6 = tab[(size_t)c6 * 8 + q8], v7 = tab[(size_t)c7 * 8 + q8];
    a[0] += ((blo(v0.x) + blo(v1.x)) + (blo(v2.x) + blo(v3.x)))
          + ((blo(v4.x) + blo(v5.x)) + (blo(v6.x) + blo(v7.x)));
    a[1] += ((bhi(v0.x) + bhi(v1.x)) + (bhi(v2.x) + bhi(v3.x)))
          + ((bhi(v4.x) + bhi(v5.x)) + (bhi(v6.x) + bhi(v7.x)));
    a[2] += ((blo(v0.y) + blo(v1.y)) + (blo(v2.y) + blo(v3.y)))
          + ((blo(v4.y) + blo(v5.y)) + (blo(v6.y) + blo(v7.y)));
    a[3] += ((bhi(v0.y) + bhi(v1.y)) + (bhi(v2.y) + bhi(v3.y)))
          + ((bhi(v4.y) + bhi(v5.y)) + (bhi(v6.y) + bhi(v7.y)));
    a[4] += ((blo(v0.z) + blo(v1.z)) + (blo(v2.z) + blo(v3.z)))
          + ((blo(v4.z) + blo(v5.z)) + (blo(v6.z) + blo(v7.z)));
    a[5] += ((bhi(v0.z) + bhi(v1.z)) + (bhi(v2.z) + bhi(v3.z)))
          + ((bhi(v4.z) + bhi(v5.z)) + (bhi(v6.z) + bhi(v7.z)));
    a[6] += ((blo(v0.w) + blo(v1.w)) + (blo(v2.w) + blo(v3.w)))
          + ((blo(v4.w) + blo(v5.w)) + (blo(v6.w) + blo(v7.w)));
    a[7] += ((bhi(v0.w) + bhi(v1.w)) + (bhi(v2.w) + bhi(v3.w)))
          + ((bhi(v4.w) + bhi(v5.w)) + (bhi(v6.w) + bhi(v7.w)));
  }
  for (; t + 4 <= m; t += 4) {
    int c0 = cp[t], c1 = cp[t + 1], c2 = cp[t + 2], c3 = cp[t + 3];
    uint4 v0 = tab[(size_t)c0 * 8 + q8], v1 = tab[(size_t)c1 * 8 + q8];
    uint4 v2 = tab[(size_t)c2 * 8 + q8], v3 = tab[(size_t)c3 * 8 + q8];
    a[0] += (blo(v0.x) + blo(v1.x)) + (blo(v2.x) + blo(v3.x));
    a[1] += (bhi(v0.x) + bhi(v1.x)) + (bhi(v2.x) + bhi(v3.x));
    a[2] += (blo(v0.y) + blo(v1.y)) + (blo(v2.y) + blo(v3.y));
    a[3] += (bhi(v0.y) + bhi(v1.y)) + (bhi(v2.y) + bhi(v3.y));
    a[4] += (blo(v0.z) + blo(v1.z)) + (blo(v2.z) + blo(v3.z));
    a[5] += (bhi(v0.z) + bhi(v1.z)) + (bhi(v2.z) + bhi(v3.z));
    a[6] += (blo(v0.w) + blo(v1.w)) + (blo(v2.w) + blo(v3.w));
    a[7] += (bhi(v0.w) + bhi(v1.w)) + (bhi(v2.w) + bhi(v3.w));
  }
  for (; t < m; ++t) {
    uint4 v = tab[(size_t)cp[t] * 8 + q8];
    a[0] += blo(v.x); a[1] += bhi(v.x); a[2] += blo(v.y); a[3] += bhi(v.y);
    a[4] += blo(v.z); a[5] += bhi(v.z); a[6] += blo(v.w); a[7] += bhi(v.w);
  }
}

// --- pass1: block-local counting sort by bucket, coalesced write-out ---
__global__ __launch_bounds__(256) void k_pass1(const int* __restrict__ src,
                                               const int* __restrict__ dst,
                                               int* __restrict__ gcur,
                                               int* __restrict__ P,
                                               int E, int nc, int seg) {
  __shared__ int hist[MAXC];
  __shared__ int lofs[MAXC];
  __shared__ int base[MAXC];
  __shared__ int sbuf[SEG];
  __shared__ unsigned short dbuf[SEG];
  __shared__ int wsum[4];
  int tid = threadIdx.x;
  int lane = tid & 63, wv = tid >> 6;
  int start = blockIdx.x * seg;
  int end = min(E, start + seg);
  int cnt = end - start;
  if (cnt <= 0) return;
  for (int i = tid; i < MAXC; i += 256) hist[i] = 0;
  __syncthreads();
  for (int i = start + tid; i < end; i += 256)
    atomicAdd(&hist[dst[i] >> 8], 1);
  __syncthreads();
  int p0 = hist[2 * tid], p1 = hist[2 * tid + 1];
  int ps = p0 + p1;
  // wave-shuffle inclusive scan over 256 threads (1 barrier)
  int incl = ps;
#pragma unroll
  for (int off = 1; off < 64; off <<= 1) {
    int t = __shfl_up(incl, off);
    if (lane >= off) incl += t;
  }
  if (lane == 63) wsum[wv] = incl;
  __syncthreads();
  int addv = 0;
#pragma unroll
  for (int w = 0; w < 3; ++w)
    if (w < wv) addv += wsum[w];
  incl += addv;
  int pe = incl - ps;
  lofs[2 * tid] = pe;
  lofs[2 * tid + 1] = pe + p0;
  __syncthreads();
  for (int b = tid; b < nc; b += 256) {
    int h = hist[b];
    base[b] = (h ? (b * CAP + atomicAdd(&gcur[b * GPAD], h)) : 0) - lofs[b];
  }
  __syncthreads();
  for (int i = tid; i < MAXC; i += 256) hist[i] = lofs[i];
  __syncthreads();
  for (int i = start + tid; i < end; i += 256) {
    int d = dst[i];
    int b = d >> 8;
    int r = atomicAdd(&hist[b], 1);
    sbuf[r] = src[i] | ((d & 255) << 17);
    dbuf[r] = (unsigned short)b;
  }
  __syncthreads();
  for (int j = tid; j < cnt; j += 256) {
    P[base[dbuf[j]] + j] = sbuf[j];
  }
}

// --- per-bucket: LDS count+scan -> rs/c/dinv, place col, then cast xh ---
__global__ __launch_bounds__(256) void k_pass2(const int* __restrict__ P,
                                               const int* __restrict__ gcur,
                                               int* __restrict__ rs,
                                               int* __restrict__ c,
                                               float* __restrict__ dinv,
                                               int* __restrict__ col,
                                               const float* __restrict__ x,
                                               unsigned int* __restrict__ xh,
                                               int N) {
  __shared__ int sh[256];
  __shared__ int lcur[256];
  __shared__ float sdi[256];
  __shared__ int wsum[4];
  int tid = threadIdx.x;
  int lane = tid & 63, wv = tid >> 6;
  int node0 = blockIdx.x << 8;
  int begin = blockIdx.x * CAP;
  int end = begin + gcur[blockIdx.x * GPAD];
  sh[tid] = 0;
  __syncthreads();
  for (int i = begin + tid; i < end; i += 256)
    atomicAdd(&sh[P[i] >> 17], 1);
  __syncthreads();
  int s = sh[tid];
  int incl = s;
#pragma unroll
  for (int off = 1; off < 64; off <<= 1) {
    int t = __shfl_up(incl, off);
    if (lane >= off) incl += t;
  }
  if (lane == 63) wsum[wv] = incl;
  __syncthreads();
  int addv = 0;
#pragma unroll
  for (int w = 0; w < 3; ++w)
    if (w < wv) addv += wsum[w];
  incl += addv;
  int excl = incl - s;
  int node = node0 + tid;
  float di = rsqrtf((float)(s + 1));
  sdi[tid] = di;
  if (node < N) {
    rs[node] = begin + excl;
    c[node] = s;
    dinv[node] = di;
  }
  lcur[tid] = begin + excl;
  __syncthreads();
  for (int i = begin + tid; i < end; i += 256) {
    int p = P[i];
    int pos = atomicAdd(&lcur[p >> 17], 1);
    col[pos] = p & 0x1FFFF;
  }
  // fused cast: xh[node] = bf16(dinv[node] * x[node]) for this block's nodes
  int nrem = min(256, N - node0);
  if (nrem <= 0) return;
  for (int i = tid; i < nrem * 16; i += 256) {
    int r = i >> 4, qq = i & 15;
    float d2 = sdi[r];
    float4 v = reinterpret_cast<const float4*>(x)[(size_t)(node0 + r) * 16 + qq];
    uint2 o;
    o.x = (unsigned int)f2b(v.x * d2) | ((unsigned int)f2b(v.y * d2) << 16);
    o.y = (unsigned int)f2b(v.z * d2) | ((unsigned int)f2b(v.w * d2) << 16);
    reinterpret_cast<uint2*>(xh)[(size_t)(node0 + r) * 16 + qq] = o;
  }
}

// --- pull1: 8-lane group per node, uint4 gathers ---
__global__ __launch_bounds__(256) void k_pull1(const unsigned int* __restrict__ xh,
                                               const int* __restrict__ rs,
                                               const int* __restrict__ cnt,
                                               const int* __restrict__ col,
                                               const float* __restrict__ dinv,
                                               unsigned int* __restrict__ aggh,
                                               int n) {
  int tid = threadIdx.x;
  int q8 = tid & 7;
  int node = (blockIdx.x * 256 + tid) >> 3;  // 32 nodes per block
  bool valid = node < n;
  int nidx = valid ? node : 0;
  int start = rs[nidx];
  int m = valid ? cnt[nidx] : 0;
  const uint4* xr = reinterpret_cast<const uint4*>(xh);
  float a[8] = {0.f, 0.f, 0.f, 0.f, 0.f, 0.f, 0.f, 0.f};
  gacc8(xr, col + start, m, q8, a);
  if (valid) {
    uint4 sv = xr[(size_t)node * 8 + q8];  // self term: xh = bf16(di*x)
    a[0] += blo(sv.x); a[1] += bhi(sv.x); a[2] += blo(sv.y); a[3] += bhi(sv.y);
    a[4] += blo(sv.z); a[5] += bhi(sv.z); a[6] += blo(sv.w); a[7] += bhi(sv.w);
    float di = dinv[node];
    uint4 o;
    o.x = (unsigned int)f2b(a[0] * di) | ((unsigned int)f2b(a[1] * di) << 16);
    o.y = (unsigned int)f2b(a[2] * di) | ((unsigned int)f2b(a[3] * di) << 16);
    o.z = (unsigned int)f2b(a[4] * di) | ((unsigned int)f2b(a[5] * di) << 16);
    o.w = (unsigned int)f2b(a[6] * di) | ((unsigned int)f2b(a[7] * di) << 16);
    reinterpret_cast<uint4*>(aggh)[(size_t)node * 8 + q8] = o;
  }
}

// --- fused gemm12: g2h = bf16(dinv ⊙ relu(aggh@W1+b1)@W2), bf16 MFMA ---
// LDS (80KB, 2 blocks/CU): aggh[128][64]bf16 @0, W1t[128][64]bf16 @16K,
// W2t[64][128]bf16 @32K, h1[128][128]bf16 / C2[128][64]f32 (reused) @48K.
// All tiles XOR-swizzled (T2).
#define OFF_W1T 16384
#define OFF_W2T 32768
#define OFF_H1  49152
__global__ __launch_bounds__(256) void k_gemm12(
    const unsigned int* __restrict__ aggh,
    const float* __restrict__ W1, const float* __restrict__ b1,
    const float* __restrict__ W2, const float* __restrict__ dinv,
    unsigned int* __restrict__ g2h, int n) {
  __shared__ __align__(16) char smem[81920];
  int tid = threadIdx.x;
  int lane = tid & 63;
  int wid = tid >> 6;
  int lr = lane & 15, lg = lane >> 4;
  int wr = wid >> 1, wc = wid & 1;
  // stage W1t bf16 [ncol=128][k=64]
  {
    int nrow = tid >> 1, h = tid & 1;
    unsigned int pk[16];
#pragma unroll
    for (int q = 0; q < 16; ++q) {
      unsigned short a = f2b(W1[(size_t)(h * 32 + 2 * q) * 128 + nrow]);
      unsigned short bq = f2b(W1[(size_t)(h * 32 + 2 * q + 1) * 128 + nrow]);
      pk[q] = (unsigned int)a | ((unsigned int)bq << 16);
    }
#pragma unroll
    for (int cc = 0; cc < 4; ++cc) {
      uint4 v = make_uint4(pk[cc * 4], pk[cc * 4 + 1], pk[cc * 4 + 2], pk[cc * 4 + 3]);
      int byte = nrow * 128 + ((h * 64 + cc * 16) ^ ((nrow & 7) << 4));
      *reinterpret_cast<uint4*>(smem + OFF_W1T + byte) = v;
    }
  }
  // stage W2t bf16 [ncol=64][k=128]
  {
    int nrow = tid >> 2, qt = tid & 3;
    unsigned int pk[16];
#pragma unroll
    for (int q = 0; q < 16; ++q) {
      unsigned short a = f2b(W2[(size_t)(qt * 32 + 2 * q) * 64 + nrow]);
      unsigned short bq = f2b(W2[(size_t)(qt * 32 + 2 * q + 1) * 64 + nrow]);
      pk[q] = (unsigned int)a | ((unsigned int)bq << 16);
    }
#pragma unroll
    for (int cc = 0; cc < 4; ++cc) {
      uint4 v = make_uint4(pk[cc * 4], pk[cc * 4 + 1], pk[cc * 4 + 2], pk[cc * 4 + 3]);
      int byte = nrow * 256 + ((qt * 64 + cc * 16) ^ ((nrow & 7) << 4));
      *reinterpret_cast<uint4*>(smem + OFF_W2T + byte) = v;
    }
  }
  float bias[4];
#pragma unroll
  for (int ni = 0; ni < 4; ++ni) bias[ni] = b1[wc * 64 + ni * 16 + lr];

  int ntiles = (n + 127) >> 7;
  for (int tile = blockIdx.x; tile < ntiles; tile += gridDim.x) {
    int row0 = tile << 7;
    __syncthreads();
#pragma unroll
    for (int j = 0; j < 4; ++j) {
      int idx = tid + 256 * j;
      int r = idx >> 3, u = idx & 7;
      uint4 v = make_uint4(0u, 0u, 0u, 0u);
      int row = row0 + r;
      if (row < n) v = reinterpret_cast<const uint4*>(aggh)[(size_t)row * 8 + u];
      int byte = r * 128 + ((u * 16) ^ ((r & 7) << 4));
      *reinterpret_cast<uint4*>(smem + byte) = v;
    }
    __syncthreads();
    f32x4 acc1[4][4];
#pragma unroll
    for (int mi = 0; mi < 4; ++mi)
#pragma unroll
      for (int ni = 0; ni < 4; ++ni) {
        f32x4 z = {0.f, 0.f, 0.f, 0.f};
        acc1[mi][ni] = z;
      }
#pragma unroll
    for (int kk = 0; kk < 2; ++kk) {
      int kb = kk * 64 + lg * 16;
      bf16x8 af[4], bfq[4];
#pragma unroll
      for (int mi = 0; mi < 4; ++mi) {
        int r = wr * 64 + mi * 16 + lr;
        af[mi] = *reinterpret_cast<const bf16x8*>(smem + r * 128 + (kb ^ ((r & 7) << 4)));
      }
#pragma unroll
      for (int ni = 0; ni < 4; ++ni) {
        int nr = wc * 64 + ni * 16 + lr;
        bfq[ni] = *reinterpret_cast<const bf16x8*>(smem + OFF_W1T + nr * 128 + (kb ^ ((nr & 7) << 4)));
      }
#pragma unroll
      for (int mi = 0; mi < 4; ++mi)
#pragma unroll
        for (int ni = 0; ni < 4; ++ni)
          acc1[mi][ni] = __builtin_amdgcn_mfma_f32_16x16x32_bf16(
              af[mi], bfq[ni], acc1[mi][ni], 0, 0, 0);
    }
#pragma unroll
    for (int mi = 0; mi < 4; ++mi) {
      int m0 = wr * 64 + mi * 16 + lg * 4;
#pragma unroll
      for (int ni = 0; ni < 4; ++ni) {
        int kcol = wc * 64 + ni * 16 + lr;
#pragma unroll
        for (int rj = 0; rj < 4; ++rj) {
          float v = fmaxf(acc1[mi][ni][rj] + bias[ni], 0.f);
          int mm = m0 + rj;
          int byte = mm * 256 + ((kcol * 2) ^ ((mm & 15) << 4));
          *reinterpret_cast<unsigned short*>(smem + OFF_H1 + byte) = f2b(v);
        }
      }
    }
    __syncthreads();
    f32x4 acc2[4][2];
#pragma unroll
    for (int mi = 0; mi < 4; ++mi)
#pragma unroll
      for (int ni = 0; ni < 2; ++ni) {
        f32x4 z = {0.f, 0.f, 0.f, 0.f};
        acc2[mi][ni] = z;
      }
#pragma unroll
    for (int kk = 0; kk < 4; ++kk) {
      int kb = kk * 64 + lg * 16;
      bf16x8 af[4], bfq[2];
#pragma unroll
      for (int mi = 0; mi < 4; ++mi) {
        int m = wr * 64 + mi * 16 + lr;
        af[mi] = *reinterpret_cast<const bf16x8*>(smem + OFF_H1 + m * 256 + (kb ^ ((m & 15) << 4)));
      }
#pragma unroll
      for (int ni = 0; ni < 2; ++ni) {
        int nr = wc * 32 + ni * 16 + lr;
        bfq[ni] = *reinterpret_cast<const bf16x8*>(smem + OFF_W2T + nr * 256 + (kb ^ ((nr & 7) << 4)));
      }
#pragma unroll
      for (int mi = 0; mi < 4; ++mi)
#pragma unroll
        for (int ni = 0; ni < 2; ++ni)
          acc2[mi][ni] = __builtin_amdgcn_mfma_f32_16x16x32_bf16(
              af[mi], bfq[ni], acc2[mi][ni], 0, 0, 0);
    }
    __syncthreads();
#pragma unroll
    for (int mi = 0; mi < 4; ++mi) {
      int m0 = wr * 64 + mi * 16 + lg * 4;
#pragma unroll
      for (int ni = 0; ni < 2; ++ni) {
        int nn = wc * 32 + ni * 16 + lr;
#pragma unroll
        for (int rj = 0; rj < 4; ++rj) {
          int mm = m0 + rj;
          int byte = mm * 256 + ((nn * 4) ^ ((mm & 15) << 4));
          *reinterpret_cast<float*>(smem + OFF_H1 + byte) = acc2[mi][ni][rj];
        }
      }
    }
    __syncthreads();
#pragma unroll
    for (int j = 0; j < 8; ++j) {
      int idx = tid + 256 * j;
      int r = idx >> 4, c4 = idx & 15;
      int row = row0 + r;
      if (row < n) {
        float4 v = *reinterpret_cast<const float4*>(
            smem + OFF_H1 + r * 256 + ((c4 * 16) ^ ((r & 15) << 4)));
        float di = dinv[row];
        uint2 o;
        o.x = (unsigned int)f2b(v.x * di) | ((unsigned int)f2b(v.y * di) << 16);
        o.y = (unsigned int)f2b(v.z * di) | ((unsigned int)f2b(v.w * di) << 16);
        reinterpret_cast<uint2*>(g2h)[(size_t)row * 16 + c4] = o;
      }
    }
  }
}

// --- pull2: 8-lane group per node, uint4 gathers, relu + both heads ---
__global__ __launch_bounds__(256) void k_pull2(const unsigned int* __restrict__ g2h,
                                               const int* __restrict__ rs,
                                               const int* __restrict__ cnt,
                                               const int* __restrict__ col,
                                               const float* __restrict__ dinv,
                                               const float* __restrict__ b,
                                               const float* __restrict__ Wd,
                                               const float* __restrict__ Wp,
                                               const float* __restrict__ bd,
                                               const float* __restrict__ bp,
                                               float* __restrict__ out, int n) {
  int tid = threadIdx.x;
  int q8 = tid & 7;
  int node = (blockIdx.x * 256 + tid) >> 3;
  bool valid = node < n;
  int nidx = valid ? node : 0;
  int start = rs[nidx];
  int m = valid ? cnt[nidx] : 0;
  const uint4* gr = reinterpret_cast<const uint4*>(g2h);
  float a[8] = {0.f, 0.f, 0.f, 0.f, 0.f, 0.f, 0.f, 0.f};
  gacc8(gr, col + start, m, q8, a);
  {
    uint4 sv = gr[(size_t)nidx * 8 + q8];  // self term
    a[0] += blo(sv.x); a[1] += bhi(sv.x); a[2] += blo(sv.y); a[3] += bhi(sv.y);
    a[4] += blo(sv.z); a[5] += bhi(sv.z); a[6] += blo(sv.w); a[7] += bhi(sv.w);
  }
  float di = dinv[nidx];
  float4 bA = *reinterpret_cast<const float4*>(b + q8 * 8);
  float4 bB = *reinterpret_cast<const float4*>(b + q8 * 8 + 4);
  float4 wdA = *reinterpret_cast<const float4*>(Wd + q8 * 8);
  float4 wdB = *reinterpret_cast<const float4*>(Wd + q8 * 8 + 4);
  float4 wpA = *reinterpret_cast<const float4*>(Wp + q8 * 8);
  float4 wpB = *reinterpret_cast<const float4*>(Wp + q8 * 8 + 4);
  float v0 = fmaxf(fmaf(a[0], di, bA.x), 0.f);
  float v1 = fmaxf(fmaf(a[1], di, bA.y), 0.f);
  float v2 = fmaxf(fmaf(a[2], di, bA.z), 0.f);
  float v3 = fmaxf(fmaf(a[3], di, bA.w), 0.f);
  float v4 = fmaxf(fmaf(a[4], di, bB.x), 0.f);
  float v5 = fmaxf(fmaf(a[5], di, bB.y), 0.f);
  float v6 = fmaxf(fmaf(a[6], di, bB.z), 0.f);
  float v7 = fmaxf(fmaf(a[7], di, bB.w), 0.f);
  float dsum = ((v0 * wdA.x + v1 * wdA.y) + (v2 * wdA.z + v3 * wdA.w))
             + ((v4 * wdB.x + v5 * wdB.y) + (v6 * wdB.z + v7 * wdB.w));
  float psum = ((v0 * wpA.x + v1 * wpA.y) + (v2 * wpA.z + v3 * wpA.w))
             + ((v4 * wpB.x + v5 * wpB.y) + (v6 * wpB.z + v7 * wpB.w));
#pragma unroll
  for (int off = 1; off < 8; off <<= 1) {
    dsum += __shfl_xor(dsum, off);
    psum += __shfl_xor(psum, off);
  }
  if (valid && q8 == 0) {
    out[node] = dsum + bd[0];
    out[n + node] = psum + bp[0];
  }
}

extern "C" void kernel_launch(void* const* d_in, const int* in_sizes, int n_in,
                              void* d_out, int out_size, void* d_ws, size_t ws_size,
                              hipStream_t stream) {
  const float* x  = (const float*)d_in[0];
  const int*   ei = (const int*)d_in[1];
  const float* W1 = (const float*)d_in[2];
  const float* b1 = (const float*)d_in[3];
  const float* W2 = (const float*)d_in[4];
  const float* b2 = (const float*)d_in[5];
  const float* Wd = (const float*)d_in[6];
  const float* bd = (const float*)d_in[7];
  const float* Wp = (const float*)d_in[8];
  const float* bp = (const float*)d_in[9];
  float* out = (float*)d_out;

  const int N = in_sizes[0] / 64;
  const int E = in_sizes[1] / 2;
  const int* src = ei;
  const int* dst = ei + E;
  const int nc = (N + 255) >> 8;

  char* ws = (char*)d_ws;
  size_t off = 0;
  auto alloc = [&](size_t bytes) -> void* {
    size_t a = (off + 255) & ~(size_t)255;
    off = a + bytes;
    return (void*)(ws + a);
  };

  int*   gcur = (int*)alloc((size_t)MAXC * GPAD * 4);
  int*   rs   = (int*)alloc((size_t)N * 4);
  int*   c    = (int*)alloc((size_t)N * 4);
  float* dinv = (float*)alloc((size_t)N * 4);
  int*   P    = (int*)alloc((size_t)nc * CAP * 4);
  int*   col  = (int*)alloc((size_t)nc * CAP * 4);
  unsigned int* xh   = (unsigned int*)alloc((size_t)N * 64 * 2);
  unsigned int* aggh = (unsigned int*)alloc((size_t)N * 64 * 2);
  unsigned int* g2h  = (unsigned int*)alloc((size_t)N * 64 * 2);
  (void)ws_size; (void)n_in; (void)out_size;

  // relative cursors: zero-init via async memset (no k_binit launch)
  hipMemsetAsync(gcur, 0, (size_t)MAXC * GPAD * 4, stream);

  int nb1 = 512;
  int seg = (E + nb1 - 1) / nb1;
  while (seg > SEG) { nb1 *= 2; seg = (E + nb1 - 1) / nb1; }
  k_pass1<<<nb1, 256, 0, stream>>>(src, dst, gcur, P, E, nc, seg);
  k_pass2<<<nc, 256, 0, stream>>>(P, gcur, rs, c, dinv, col, x, xh, N);

  k_pull1<<<(N + 31) / 32, 256, 0, stream>>>(xh, rs, c, col, dinv, aggh, N);
  k_gemm12<<<512, 256, 0, stream>>>(aggh, W1, b1, W2, dinv, g2h, N);
  k_pull2<<<(N + 31) / 32, 256, 0, stream>>>(g2h, rs, c, col, dinv, b2, Wd, Wp, bd, bp, out, N);
}